// Round 2
// baseline (4743.758 us; speedup 1.0000x reference)
//
#include <hip/hip_runtime.h>

// TimeLSTM persistent kernel for MI355X (gfx950).  B=128, S=512, I=256, H=512.
// 256 blocks x 256 threads, plain launch (grid == CU count -> co-resident).
//   group gq = blockIdx%8 -> batch rows [gq*16, gq*16+16)  (8 independent groups)
//   slice s  = blockIdx/8 -> H columns [s*16, s*16+16)     (32 slices/group)
// Weight-stationary (112 VGPRs of bf16 B-fragments per wave).
//
// Round-2 == Round-1 design (round-1 bench was an infra failure, no signal):
// 2 barriers/step (was 5).
//  - hc exchange: separate contiguous bf16 h[16][512] / c[16][512] arrays per
//    group+parity. Writers pack neighbor pairs via shfl_xor (1 u32 store per
//    thread). Readers: 8+8 coalesced u64 agent-relaxed loads -> 16 ds_write_b64
//    (no unpack VALU, no b16 LDS writes).
//  - x staging: global->reg dwordx4 (issued in previous step's tail, hides
//    under the flag poll), in-reg f32->bf16, 2 ds_write_b128. No gl_lds, no
//    fp32 LDS staging buffer, no convert barrier.
//  - flags: per-WAVE slots (32 blocks x 4 waves = 128/group). Each wave drains
//    its own stores (s_waitcnt vmcnt(0)) then lane0 stores its flag; ALL waves
//    poll independently and fall through into next step's loads (no barrier
//    around the flag protocol). Ordering: flag>=t+1 => that wave's parity-p'
//    stores are ack'd at the coherence point; its parity-p reads were consumed
//    before it flagged, so the 2-parity WAR hazard stays closed.
//  - poll backoff s_sleep(2) (matches proven baseline) to keep spin-load LLC
//    traffic off the hc-exchange critical path.

#define Bq 128
#define Sq 512
#define Iq 256
#define Hq 512

typedef __bf16  bf16x8  __attribute__((ext_vector_type(8)));
typedef float   floatx4 __attribute__((ext_vector_type(4)));
typedef unsigned short ushort;
typedef ushort  ushort8 __attribute__((ext_vector_type(8)));
typedef unsigned long long u64;

__device__ __forceinline__ ushort f2bf(float f) {
    union { float f; unsigned u; } v; v.f = f;
    unsigned r = v.u + 0x7fffu + ((v.u >> 16) & 1u);   // RNE
    return (ushort)(r >> 16);
}

__device__ __forceinline__ float sigm(float x) { return 1.f / (1.f + __expf(-x)); }
__device__ __forceinline__ float tanh_fast(float x) {
    float e = __expf(2.f * x);
    return 1.f - 2.f / (e + 1.f);
}

__device__ __forceinline__ bf16x8 pack8(float4 a, float4 b) {
    ushort8 v;
    v[0] = f2bf(a.x); v[1] = f2bf(a.y); v[2] = f2bf(a.z); v[3] = f2bf(a.w);
    v[4] = f2bf(b.x); v[5] = f2bf(b.y); v[6] = f2bf(b.z); v[7] = f2bf(b.w);
    return __builtin_bit_cast(bf16x8, v);
}

// ---------------- main persistent kernel ----------------
__global__ __launch_bounds__(256, 1) void lstm_kernel(
    const float* __restrict__ xin,
    const float* __restrict__ tsp,
    const float* __restrict__ Ww, const float* __restrict__ Wb,
    const float* __restrict__ Uw, const float* __restrict__ Ub,
    const float* __restrict__ Dw, const float* __restrict__ Db,
    unsigned* __restrict__ hcbuf,      // [parity][group][ h:4096 u32 | c:4096 u32 ]
    unsigned* __restrict__ slots,      // [group][128] u32 per-wave flags
    float* __restrict__ out)
{
    __shared__ ushort h_s[16 * 520];   // +8 shorts row pad
    __shared__ ushort c_s[16 * 520];
    __shared__ ushort x_s[16 * 264];   // bf16 x tile
    __shared__ float  gb[4 * 256];     // gate preactivations
    __shared__ float  gd[4 * 256];     // W_d K-quarter partials
    __shared__ float  bias_g[64];
    __shared__ float  bias_d[16];

    const int tid  = threadIdx.x;
    const int lane = tid & 63;
    const int wv   = tid >> 6;         // wave id == gate id
    const int n    = lane & 15;
    const int quad = lane >> 4;
    const int gq   = blockIdx.x & 7;   // batch group
    const int s    = blockIdx.x >> 3;  // column slice 0..31
    const int jj   = s * 16;

    // ---- stationary B-fragments ----
    bf16x8 bW[16], bU[8], bD[4];
    {
        const int Rw = wv * Hq + jj + n;
        #pragma unroll
        for (int kk = 0; kk < 16; ++kk) {
            const float4* p = (const float4*)(Ww + (size_t)Rw * Hq + kk * 32 + quad * 8);
            bW[kk] = pack8(p[0], p[1]);
        }
        #pragma unroll
        for (int kk = 0; kk < 8; ++kk) {
            const float4* p = (const float4*)(Uw + (size_t)Rw * Iq + kk * 32 + quad * 8);
            bU[kk] = pack8(p[0], p[1]);
        }
        const int Rd = jj + n;
        #pragma unroll
        for (int kq = 0; kq < 4; ++kq) {
            const float4* p = (const float4*)(Dw + (size_t)Rd * Hq + (wv * 4 + kq) * 32 + quad * 8);
            bD[kq] = pack8(p[0], p[1]);
        }
    }
    if (tid < 64)
        bias_g[tid] = Wb[(tid >> 4) * Hq + jj + (tid & 15)] + Ub[(tid >> 4) * Hq + jj + (tid & 15)];
    if (tid >= 64 && tid < 80)
        bias_d[tid - 64] = Db[jj + (tid - 64)];
    __syncthreads();

    float c_reg = 0.f;                 // fp32 cell state for (b=tid>>4, j=tid&15)
    const int b = tid >> 4, j = tid & 15;
    const int grow = gq * 16 + b;

    const ushort* hp = &h_s[n * 520 + quad * 8];
    const ushort* cp = &c_s[n * 520 + quad * 8];
    const ushort* xp = &x_s[n * 264 + quad * 8];

    unsigned* flagbase = slots + gq * 128;
    unsigned* myflag   = flagbase + s * 4 + wv;          // lane0-of-wave writes
    const unsigned* poll0 = flagbase + lane;
    const unsigned* poll1 = flagbase + 64 + lane;

    // x register staging: thread handles row r=tid>>4 of group tile, 16 floats
    const float* xbase = xin + ((size_t)(gq * 16 + (tid >> 4)) * Sq) * Iq + (tid & 15) * 16;
    float4 x0, x1, x2, x3;
    {   // prologue prefetch for t=0
        const float4* p = (const float4*)xbase;
        x0 = p[0]; x1 = p[1]; x2 = p[2]; x3 = p[3];
    }

    for (int t = 0; t < Sq; ++t) {
        float tt = tsp[(size_t)grow * Sq + t];

        // ---- phase B: load hc (coherent u64), convert x, fill LDS ----
        const u64* hsrc = (const u64*)(hcbuf + ((size_t)(t & 1) * 8 + gq) * 8192);
        const u64* csrc = hsrc + 2048;
        u64 hv[8], cv[8];
        #pragma unroll
        for (int k = 0; k < 8; ++k)
            hv[k] = __hip_atomic_load(hsrc + k * 256 + tid, __ATOMIC_RELAXED, __HIP_MEMORY_SCOPE_AGENT);
        #pragma unroll
        for (int k = 0; k < 8; ++k)
            cv[k] = __hip_atomic_load(csrc + k * 256 + tid, __ATOMIC_RELAXED, __HIP_MEMORY_SCOPE_AGENT);

        // x fp32 -> bf16 (registers loaded in previous step's tail)
        {
            bf16x8 v0 = pack8(x0, x1);
            bf16x8 v1 = pack8(x2, x3);
            ushort* xd = &x_s[(tid >> 4) * 264 + (tid & 15) * 16];
            *(bf16x8*)xd       = v0;
            *(bf16x8*)(xd + 8) = v1;
        }

        // hc -> LDS, direct b64 stores (4 consecutive bf16 per u64)
        #pragma unroll
        for (int k = 0; k < 8; ++k) {
            const int m   = k * 256 + tid;       // u64 index in [0,2048)
            const int row = m >> 7;              // (4m)>>9
            const int col = (m << 2) & 511;
            *(u64*)&h_s[row * 520 + col] = hv[k];
            *(u64*)&c_s[row * 520 + col] = cv[k];
        }
        __syncthreads();                         // barrier 1: LDS tiles ready

        // ---- phase C: MFMA ----
        floatx4 accW = {0.f, 0.f, 0.f, 0.f};
        floatx4 accU = {0.f, 0.f, 0.f, 0.f};
        floatx4 accD = {0.f, 0.f, 0.f, 0.f};
        #pragma unroll
        for (int kk = 0; kk < 16; ++kk) {
            bf16x8 ah = *(const bf16x8*)(hp + kk * 32);
            accW = __builtin_amdgcn_mfma_f32_16x16x32_bf16(ah, bW[kk], accW, 0, 0, 0);
            if (kk < 8) {
                bf16x8 ax = *(const bf16x8*)(xp + kk * 32);
                accU = __builtin_amdgcn_mfma_f32_16x16x32_bf16(ax, bU[kk], accU, 0, 0, 0);
            }
            if ((kk >> 2) == wv) {
                bf16x8 ac = *(const bf16x8*)(cp + kk * 32);
                accD = __builtin_amdgcn_mfma_f32_16x16x32_bf16(ac, bD[kk & 3], accD, 0, 0, 0);
            }
        }
        accW += accU;

        #pragma unroll
        for (int r2 = 0; r2 < 4; ++r2) {
            gb[wv * 256 + (quad * 4 + r2) * 16 + n] = accW[r2];
            gd[wv * 256 + (quad * 4 + r2) * 16 + n] = accD[r2];
        }
        __syncthreads();                         // barrier 2: partials ready

        // ---- phase D: gate math + exchange stores + per-wave flag + poll ----
        float pf = gb[tid]       + bias_g[j];
        float pi = gb[256 + tid] + bias_g[16 + j];
        float po = gb[512 + tid] + bias_g[32 + j];
        float pc = gb[768 + tid] + bias_g[48 + j];
        float csum = gd[tid] + gd[256 + tid] + gd[512 + tid] + gd[768 + tid] + bias_d[j];
        float c_s1  = tanh_fast(csum);
        float c_adj = c_reg - c_s1 + c_s1 * tt;
        float fg = sigm(pf), ig = sigm(pi), og = sigm(po), cg = sigm(pc);
        float c_new = fg * c_adj + ig * cg;
        float h_new = og * tanh_fast(c_new);
        c_reg = c_new;

        out[((size_t)grow * Sq + t) * Hq + jj + j] = h_new;

        // pair-packed coherent store: even j stores h-pair, odd j stores c-pair
        {
            unsigned my    = ((unsigned)f2bf(c_new) << 16) | (unsigned)f2bf(h_new);
            unsigned other = __shfl_xor(my, 1);
            unsigned* dst  = hcbuf + ((size_t)((t + 1) & 1) * 8 + gq) * 8192;
            const int pidx = b * 256 + ((jj + j) >> 1);
            if ((j & 1) == 0) {
                unsigned hpair = ((other & 0xFFFFu) << 16) | (my & 0xFFFFu);
                __hip_atomic_store(dst + pidx, hpair, __ATOMIC_RELAXED, __HIP_MEMORY_SCOPE_AGENT);
            } else {
                unsigned cpair = (my & 0xFFFF0000u) | (other >> 16);
                __hip_atomic_store(dst + 4096 + pidx, cpair, __ATOMIC_RELAXED, __HIP_MEMORY_SCOPE_AGENT);
            }
        }

        if (t < Sq - 1) {
            // per-wave drain: this wave's hc/out stores ack'd at coherence point
            asm volatile("s_waitcnt vmcnt(0)" ::: "memory");
            const unsigned tgt = (unsigned)(t + 1);
            if (lane == 0)
                __hip_atomic_store(myflag, tgt, __ATOMIC_RELAXED, __HIP_MEMORY_SCOPE_AGENT);

            // prefetch next x tile into registers (hides under the poll)
            {
                const float4* p = (const float4*)(xbase + (size_t)(t + 1) * Iq);
                x0 = p[0]; x1 = p[1]; x2 = p[2]; x3 = p[3];
            }

            // all-wave parallel poll over 128 per-wave slots
            for (;;) {
                unsigned a0 = __hip_atomic_load(poll0, __ATOMIC_RELAXED, __HIP_MEMORY_SCOPE_AGENT);
                unsigned a1 = __hip_atomic_load(poll1, __ATOMIC_RELAXED, __HIP_MEMORY_SCOPE_AGENT);
                if (__all(a0 >= tgt && a1 >= tgt)) break;
                __builtin_amdgcn_s_sleep(2);
            }
            asm volatile("" ::: "memory");       // compiler fence: loads below stay below
        }
    }
}

extern "C" void kernel_launch(void* const* d_in, const int* in_sizes, int n_in,
                              void* d_out, int out_size, void* d_ws, size_t ws_size,
                              hipStream_t stream) {
    const float* inputs = (const float*)d_in[0];
    const float* tsp    = (const float*)d_in[1];
    const float* Ww     = (const float*)d_in[2];
    const float* Wb     = (const float*)d_in[3];
    const float* Uw     = (const float*)d_in[4];
    const float* Ub     = (const float*)d_in[5];
    const float* Dw     = (const float*)d_in[6];
    const float* Db     = (const float*)d_in[7];
    float* out = (float*)d_out;

    char* ws = (char*)d_ws;
    // layout: [0, 512K) hcbuf (2 parities x 8 groups x 8192 u32) | [512K, 516K) slots
    unsigned* hcbuf = (unsigned*)ws;
    unsigned* slots = (unsigned*)(ws + 524288);

    hipMemsetAsync(ws, 0, 262144, stream);          // parity-0 hc = 0 (h0 = c0 = 0)
    hipMemsetAsync(ws + 524288, 0, 4096, stream);   // 8 groups x 128 wave flags = 0

    lstm_kernel<<<dim3(256), dim3(256), 0, stream>>>(
        inputs, tsp, Ww, Wb, Uw, Ub, Dw, Db, hcbuf, slots, out);
}

// Round 3
// 1815.974 us; speedup vs baseline: 2.6122x; 2.6122x over previous
//
#include <hip/hip_runtime.h>

// TimeLSTM persistent kernel for MI355X (gfx950).  B=128, S=512, I=256, H=512.
// 256 blocks x 256 threads, plain launch (grid == CU count -> co-resident).
//   group gq = blockIdx%8 -> batch rows [gq*16, gq*16+16)  (8 independent groups)
//   slice s  = blockIdx/8 -> H columns [s*16, s*16+16)     (32 slices/group)
// Weight-stationary (112 VGPRs of bf16 B-fragments per wave).
//
// Round-3: revert to the PROVEN flag protocol (block-level slot written by
// tid0 after the full-block __syncthreads vmcnt-drain; wave-0-only poll with
// s_sleep(2); closing barrier) -- round-2's per-wave flags + all-wave poll +
// prefetch-inside-poll regressed 2.2x. Keep only the two low-risk wins:
//  - hc exchange format: separate contiguous bf16 h[16][512] / c[16][512]
//    planes per group+parity. Writers pair-pack via shfl_xor (1 u32 store per
//    thread). Readers: 8+8 coalesced u64 agent-relaxed loads -> 16
//    ds_write_b64 (no unpack VALU, no b16 LDS writes).
//  - x staging: global->reg dwordx4 issued in the step tail AFTER the flag
//    store (waves 1-3 overlap it with the barrier wait; only wave 0's poll
//    drains it), in-reg f32->bf16, 2 ds_write_b128. No gl_lds fp32 staging,
//    no convert barrier.  4 barriers/step (baseline had 5).

#define Bq 128
#define Sq 512
#define Iq 256
#define Hq 512

typedef __bf16  bf16x8  __attribute__((ext_vector_type(8)));
typedef float   floatx4 __attribute__((ext_vector_type(4)));
typedef unsigned short ushort;
typedef ushort  ushort8 __attribute__((ext_vector_type(8)));
typedef unsigned long long u64;

__device__ __forceinline__ ushort f2bf(float f) {
    union { float f; unsigned u; } v; v.f = f;
    unsigned r = v.u + 0x7fffu + ((v.u >> 16) & 1u);   // RNE
    return (ushort)(r >> 16);
}

__device__ __forceinline__ float sigm(float x) { return 1.f / (1.f + __expf(-x)); }
__device__ __forceinline__ float tanh_fast(float x) {
    float e = __expf(2.f * x);
    return 1.f - 2.f / (e + 1.f);
}

__device__ __forceinline__ bf16x8 pack8(float4 a, float4 b) {
    ushort8 v;
    v[0] = f2bf(a.x); v[1] = f2bf(a.y); v[2] = f2bf(a.z); v[3] = f2bf(a.w);
    v[4] = f2bf(b.x); v[5] = f2bf(b.y); v[6] = f2bf(b.z); v[7] = f2bf(b.w);
    return __builtin_bit_cast(bf16x8, v);
}

// ---------------- main persistent kernel ----------------
__global__ __launch_bounds__(256, 1) void lstm_kernel(
    const float* __restrict__ xin,
    const float* __restrict__ tsp,
    const float* __restrict__ Ww, const float* __restrict__ Wb,
    const float* __restrict__ Uw, const float* __restrict__ Ub,
    const float* __restrict__ Dw, const float* __restrict__ Db,
    unsigned* __restrict__ hcbuf,      // [parity][group][ h:4096 u32 | c:4096 u32 ]
    unsigned* __restrict__ slots,      // [group][64] u32 (32 used) block flags
    float* __restrict__ out)
{
    __shared__ ushort h_s[16 * 520];   // +8 shorts row pad
    __shared__ ushort c_s[16 * 520];
    __shared__ ushort x_s[16 * 264];   // bf16 x tile
    __shared__ float  gb[4 * 256];     // gate preactivations
    __shared__ float  gd[4 * 256];     // W_d K-quarter partials
    __shared__ float  bias_g[64];
    __shared__ float  bias_d[16];

    const int tid  = threadIdx.x;
    const int lane = tid & 63;
    const int wv   = tid >> 6;         // wave id == gate id
    const int n    = lane & 15;
    const int quad = lane >> 4;
    const int gq   = blockIdx.x & 7;   // batch group
    const int s    = blockIdx.x >> 3;  // column slice 0..31
    const int jj   = s * 16;

    // ---- stationary B-fragments ----
    bf16x8 bW[16], bU[8], bD[4];
    {
        const int Rw = wv * Hq + jj + n;
        #pragma unroll
        for (int kk = 0; kk < 16; ++kk) {
            const float4* p = (const float4*)(Ww + (size_t)Rw * Hq + kk * 32 + quad * 8);
            bW[kk] = pack8(p[0], p[1]);
        }
        #pragma unroll
        for (int kk = 0; kk < 8; ++kk) {
            const float4* p = (const float4*)(Uw + (size_t)Rw * Iq + kk * 32 + quad * 8);
            bU[kk] = pack8(p[0], p[1]);
        }
        const int Rd = jj + n;
        #pragma unroll
        for (int kq = 0; kq < 4; ++kq) {
            const float4* p = (const float4*)(Dw + (size_t)Rd * Hq + (wv * 4 + kq) * 32 + quad * 8);
            bD[kq] = pack8(p[0], p[1]);
        }
    }
    if (tid < 64)
        bias_g[tid] = Wb[(tid >> 4) * Hq + jj + (tid & 15)] + Ub[(tid >> 4) * Hq + jj + (tid & 15)];
    if (tid >= 64 && tid < 80)
        bias_d[tid - 64] = Db[jj + (tid - 64)];
    __syncthreads();

    float c_reg = 0.f;                 // fp32 cell state for (b=tid>>4, j=tid&15)
    const int b = tid >> 4, j = tid & 15;
    const int grow = gq * 16 + b;

    const ushort* hp = &h_s[n * 520 + quad * 8];
    const ushort* cp = &c_s[n * 520 + quad * 8];
    const ushort* xp = &x_s[n * 264 + quad * 8];

    unsigned* myslot = &slots[gq * 64 + s];
    unsigned* pollp  = &slots[gq * 64 + (lane & 31)];

    // x register staging: thread handles row r=tid>>4 of group tile, 16 floats
    const float* xbase = xin + ((size_t)(gq * 16 + (tid >> 4)) * Sq) * Iq + (tid & 15) * 16;
    float4 x0, x1, x2, x3;
    {   // prologue prefetch for t=0
        const float4* p = (const float4*)xbase;
        x0 = p[0]; x1 = p[1]; x2 = p[2]; x3 = p[3];
    }

    for (int t = 0; t < Sq; ++t) {
        float tt = tsp[(size_t)grow * Sq + t];

        // ---- phase B: load hc (coherent u64), convert x, fill LDS ----
        const u64* hsrc = (const u64*)(hcbuf + ((size_t)(t & 1) * 8 + gq) * 8192);
        const u64* csrc = hsrc + 2048;
        u64 hv[8], cv[8];
        #pragma unroll
        for (int k = 0; k < 8; ++k)
            hv[k] = __hip_atomic_load(hsrc + k * 256 + tid, __ATOMIC_RELAXED, __HIP_MEMORY_SCOPE_AGENT);
        #pragma unroll
        for (int k = 0; k < 8; ++k)
            cv[k] = __hip_atomic_load(csrc + k * 256 + tid, __ATOMIC_RELAXED, __HIP_MEMORY_SCOPE_AGENT);

        // x fp32 -> bf16 (registers loaded in previous step's tail)
        {
            bf16x8 v0 = pack8(x0, x1);
            bf16x8 v1 = pack8(x2, x3);
            ushort* xd = &x_s[(tid >> 4) * 264 + (tid & 15) * 16];
            *(bf16x8*)xd       = v0;
            *(bf16x8*)(xd + 8) = v1;
        }

        // hc -> LDS, direct b64 stores (4 consecutive bf16 per u64)
        #pragma unroll
        for (int k = 0; k < 8; ++k) {
            const int m   = k * 256 + tid;       // u64 index in [0,2048)
            const int row = m >> 7;
            const int col = (m << 2) & 511;
            *(u64*)&h_s[row * 520 + col] = hv[k];
            *(u64*)&c_s[row * 520 + col] = cv[k];
        }
        __syncthreads();                         // barrier 1: LDS tiles ready

        // ---- phase C: MFMA ----
        floatx4 accW = {0.f, 0.f, 0.f, 0.f};
        floatx4 accU = {0.f, 0.f, 0.f, 0.f};
        floatx4 accD = {0.f, 0.f, 0.f, 0.f};
        #pragma unroll
        for (int kk = 0; kk < 16; ++kk) {
            bf16x8 ah = *(const bf16x8*)(hp + kk * 32);
            accW = __builtin_amdgcn_mfma_f32_16x16x32_bf16(ah, bW[kk], accW, 0, 0, 0);
            if (kk < 8) {
                bf16x8 ax = *(const bf16x8*)(xp + kk * 32);
                accU = __builtin_amdgcn_mfma_f32_16x16x32_bf16(ax, bU[kk], accU, 0, 0, 0);
            }
            if ((kk >> 2) == wv) {
                bf16x8 ac = *(const bf16x8*)(cp + kk * 32);
                accD = __builtin_amdgcn_mfma_f32_16x16x32_bf16(ac, bD[kk & 3], accD, 0, 0, 0);
            }
        }
        accW += accU;

        #pragma unroll
        for (int r2 = 0; r2 < 4; ++r2) {
            gb[wv * 256 + (quad * 4 + r2) * 16 + n] = accW[r2];
            gd[wv * 256 + (quad * 4 + r2) * 16 + n] = accD[r2];
        }
        __syncthreads();                         // barrier 2: partials ready

        // ---- phase D: gate math + exchange stores ----
        float pf = gb[tid]       + bias_g[j];
        float pi = gb[256 + tid] + bias_g[16 + j];
        float po = gb[512 + tid] + bias_g[32 + j];
        float pc = gb[768 + tid] + bias_g[48 + j];
        float csum = gd[tid] + gd[256 + tid] + gd[512 + tid] + gd[768 + tid] + bias_d[j];
        float c_s1  = tanh_fast(csum);
        float c_adj = c_reg - c_s1 + c_s1 * tt;
        float fg = sigm(pf), ig = sigm(pi), og = sigm(po), cg = sigm(pc);
        float c_new = fg * c_adj + ig * cg;
        float h_new = og * tanh_fast(c_new);
        c_reg = c_new;

        out[((size_t)grow * Sq + t) * Hq + jj + j] = h_new;

        // pair-packed coherent store: even j stores h-pair, odd j stores c-pair
        {
            unsigned my    = ((unsigned)f2bf(c_new) << 16) | (unsigned)f2bf(h_new);
            unsigned other = __shfl_xor(my, 1);
            unsigned* dst  = hcbuf + ((size_t)((t + 1) & 1) * 8 + gq) * 8192;
            const int pidx = b * 256 + ((jj + j) >> 1);
            if ((j & 1) == 0) {
                unsigned hpair = ((other & 0xFFFFu) << 16) | (my & 0xFFFFu);
                __hip_atomic_store(dst + pidx, hpair, __ATOMIC_RELAXED, __HIP_MEMORY_SCOPE_AGENT);
            } else {
                unsigned cpair = (my & 0xFFFF0000u) | (other >> 16);
                __hip_atomic_store(dst + 4096 + pidx, cpair, __ATOMIC_RELAXED, __HIP_MEMORY_SCOPE_AGENT);
            }
        }
        __syncthreads();   // barrier 3: vmcnt(0) drain -> all block stores ack'd

        // ---- per-group flag barrier (block slot, wave-0 poll) ----
        if (t < Sq - 1) {
            const unsigned tgt = (unsigned)(t + 1);
            if (tid == 0)
                __hip_atomic_store(myslot, tgt, __ATOMIC_RELAXED, __HIP_MEMORY_SCOPE_AGENT);

            // prefetch next x tile into registers (waves 1-3 overlap with wait)
            {
                const float4* p = (const float4*)(xbase + (size_t)(t + 1) * Iq);
                x0 = p[0]; x1 = p[1]; x2 = p[2]; x3 = p[3];
            }

            if (wv == 0) {
                for (;;) {
                    unsigned vv = __hip_atomic_load(pollp, __ATOMIC_RELAXED, __HIP_MEMORY_SCOPE_AGENT);
                    if (__all(vv >= tgt)) break;
                    __builtin_amdgcn_s_sleep(2);
                }
            }
            __syncthreads();                     // barrier 4: group advanced
        }
    }
}

extern "C" void kernel_launch(void* const* d_in, const int* in_sizes, int n_in,
                              void* d_out, int out_size, void* d_ws, size_t ws_size,
                              hipStream_t stream) {
    const float* inputs = (const float*)d_in[0];
    const float* tsp    = (const float*)d_in[1];
    const float* Ww     = (const float*)d_in[2];
    const float* Wb     = (const float*)d_in[3];
    const float* Uw     = (const float*)d_in[4];
    const float* Ub     = (const float*)d_in[5];
    const float* Dw     = (const float*)d_in[6];
    const float* Db     = (const float*)d_in[7];
    float* out = (float*)d_out;

    char* ws = (char*)d_ws;
    // layout: [0, 512K) hcbuf (2 parities x 8 groups x 8192 u32) | [512K, 514K) slots
    unsigned* hcbuf = (unsigned*)ws;
    unsigned* slots = (unsigned*)(ws + 524288);

    hipMemsetAsync(ws, 0, 262144, stream);          // parity-0 hc = 0 (h0 = c0 = 0)
    hipMemsetAsync(ws + 524288, 0, 2048, stream);   // 8 groups x 64 block flags = 0

    lstm_kernel<<<dim3(256), dim3(256), 0, stream>>>(
        inputs, tsp, Ww, Wb, Uw, Ub, Dw, Db, hcbuf, slots, out);
}